// Round 4
// baseline (808.524 us; speedup 1.0000x reference)
//
#include <hip/hip_runtime.h>

#define NUM_RELS 19

// ---------------- CSR build ----------------
// cnt2[v*19+r] = #edges with dst=v, etype=r  (feeds both scan1 and layer1)

__global__ void hist2_kernel(const int* __restrict__ dst, const int* __restrict__ etype,
                             int* __restrict__ cnt2, int E) {
    int e = blockIdx.x * blockDim.x + threadIdx.x;
    if (e < E) atomicAdd(&cnt2[dst[e] * NUM_RELS + etype[e]], 1);
}

// chunk = 2048 nodes per block (256 threads x 8 nodes); per-node count = sum of 19 cnt2 entries
__global__ void scan1_kernel(const int* __restrict__ cnt2, int* __restrict__ row_start,
                             int* __restrict__ bsum, int N) {
    __shared__ int lds[256];
    int t = threadIdx.x;
    int base = blockIdx.x * 2048 + t * 8;
    int v[8];
    int s = 0;
#pragma unroll
    for (int k = 0; k < 8; ++k) {
        int c = 0;
        if (base + k < N) {
            const int* p = cnt2 + (size_t)(base + k) * NUM_RELS;
#pragma unroll
            for (int r = 0; r < NUM_RELS; ++r) c += p[r];
        }
        v[k] = c;
        s += c;
    }
    lds[t] = s;
    __syncthreads();
    for (int off = 1; off < 256; off <<= 1) {
        int x = (t >= off) ? lds[t - off] : 0;
        __syncthreads();
        lds[t] += x;
        __syncthreads();
    }
    int run = lds[t] - s;  // exclusive prefix of this thread's chunk
#pragma unroll
    for (int k = 0; k < 8; ++k) {
        if (base + k < N) row_start[base + k] = run;
        run += v[k];
    }
    if (t == 255) bsum[blockIdx.x] = lds[255];
}

__global__ void scan2_kernel(int* __restrict__ bsum, int NB) {
    __shared__ int lds[256];
    int t = threadIdx.x;
    int v = (t < NB) ? bsum[t] : 0;
    lds[t] = v;
    __syncthreads();
    for (int off = 1; off < 256; off <<= 1) {
        int x = (t >= off) ? lds[t - off] : 0;
        __syncthreads();
        lds[t] += x;
        __syncthreads();
    }
    if (t < NB) bsum[t] = lds[t] - v;  // exclusive
}

__global__ void scan3_kernel(int* __restrict__ row_start, int* __restrict__ cursor,
                             const int* __restrict__ bsum, int N, int E) {
    int i = blockIdx.x * blockDim.x + threadIdx.x;
    if (i < N) {
        int v = row_start[i] + bsum[i >> 11];
        row_start[i] = v;
        cursor[i] = v;
    } else if (i == N) {
        row_start[N] = E;
    }
}

// scatter packed edge meta (src<<5 | etype) into CSR order — ONE int per edge
__global__ void scatter_kernel(const int* __restrict__ src, const int* __restrict__ dst,
                               const int* __restrict__ etype, int* __restrict__ cursor,
                               int* __restrict__ smeta, int E) {
    int e = blockIdx.x * blockDim.x + threadIdx.x;
    if (e < E) {
        int p = atomicAdd(&cursor[dst[e]], 1);
        smeta[p] = (src[e] << 5) | etype[e];
    }
}

// ---------------- Layer 1 (closed form): h1[v][o] = relu(b1[o] + sum_r cnt2[v][r]*W1[r][o]) ----------------

__global__ __launch_bounds__(256) void layer1_kernel(
    const int* __restrict__ cnt2, const float* __restrict__ W1,
    const float* __restrict__ b1, float* __restrict__ h1, int N) {
    __shared__ float W1s[NUM_RELS * 32];
    __shared__ float b1s[32];
    for (int t = threadIdx.x; t < NUM_RELS * 32; t += blockDim.x) W1s[t] = W1[t];
    if (threadIdx.x < 32) b1s[threadIdx.x] = b1[threadIdx.x];
    __syncthreads();

    int hw = (blockIdx.x * blockDim.x + threadIdx.x) >> 5;  // node id
    int o = threadIdx.x & 31;
    if (hw >= N) return;
    const int* c = cnt2 + (size_t)hw * NUM_RELS;
    float acc = b1s[o];
#pragma unroll
    for (int r = 0; r < NUM_RELS; ++r) acc += (float)c[r] * W1s[r * 32 + o];
    h1[(size_t)hw * 32 + o] = fmaxf(acc, 0.f);
}

// ---------------- Layer 2 + 3 fused, software-pipelined ----------------
// Per 32-lane half-wave: one node, lane = output channel o.
// Ping-pong two h-rows (A/B, 8 float4 each) so edge j+1's gather overlaps edge j's FMAs.
//
// amdgpu_waves_per_eu(4,4): the 90KB LDS pins us to 1 block/CU = 16 waves = 4 waves/EU.
// Round-2/3 let the compiler target 8 waves/EU -> 64-VGPR cap -> it spilled the 64-VGPR
// A/B pipeline buffers to scratch (WRITE_SIZE 402MB / 180MB vs 12.8MB ideal). Pinning
// min=max=4 raises the VGPR budget to 128 so the pipeline actually lives in registers.

#define W2T_PAD 36
#define W2T_FLOATS (NUM_RELS * 32 * W2T_PAD)

__global__ __launch_bounds__(1024)
__attribute__((amdgpu_waves_per_eu(4, 4)))
void layer23_kernel(
    const float* __restrict__ h1, const int* __restrict__ row_start,
    const int* __restrict__ smeta,
    const float* __restrict__ W2, const float* __restrict__ b2,
    const float* __restrict__ W3, const float* __restrict__ b3,
    float* __restrict__ out, int N) {
    extern __shared__ float lds[];
    float* W2T = lds;                    // [19][32][36] (o-major, i padded)
    float* W3s = lds + W2T_FLOATS;       // [32][32]

    for (int t = threadIdx.x; t < NUM_RELS * 1024; t += blockDim.x) {
        int r = t >> 10, rem = t & 1023, i = rem >> 5, o = rem & 31;
        W2T[(r * 32 + o) * W2T_PAD + i] = W2[t];
    }
    for (int t = threadIdx.x; t < 1024; t += blockDim.x) W3s[t] = W3[t];
    __syncthreads();

    int o = threadIdx.x & 31;

    for (int v0 = blockIdx.x * 32; v0 < N; v0 += gridDim.x * 32) {
        int hw = v0 + (threadIdx.x >> 5);  // node id
        if (hw >= N) continue;
        int start = row_start[hw], end = row_start[hw + 1];

        float acc = 0.f;
        for (int base = start; base < end; base += 32) {
            int idx = base + o;
            int m_l = (idx < end) ? smeta[idx] : 0;  // coalesced packed (src<<5|etype)
            int cnt = min(32, end - base);

            float4 A[8], B[8];
            int m0 = __shfl(m_l, 0, 32);
            int rA = m0 & 31;
            {
                const float4* hp = (const float4*)(h1 + (size_t)(m0 >> 5) * 32);
#pragma unroll
                for (int c = 0; c < 8; ++c) A[c] = hp[c];
            }
            int j = 0;
            while (j + 1 < cnt) {
                int mB = __shfl(m_l, j + 1, 32);
                int rB = mB & 31;
                {
                    const float4* hp = (const float4*)(h1 + (size_t)(mB >> 5) * 32);
#pragma unroll
                    for (int c = 0; c < 8; ++c) B[c] = hp[c];
                }
                {  // compute edge j from A
                    const float* wp = W2T + (rA * 32 + o) * W2T_PAD;
#pragma unroll
                    for (int c = 0; c < 8; ++c) {
                        float4 w4 = *(const float4*)(wp + c * 4);
                        acc = fmaf(A[c].x, w4.x, acc);
                        acc = fmaf(A[c].y, w4.y, acc);
                        acc = fmaf(A[c].z, w4.z, acc);
                        acc = fmaf(A[c].w, w4.w, acc);
                    }
                }
                {  // prefetch edge min(j+2, cnt-1) into A (clamped: no divergent branch)
                    int jn = min(j + 2, cnt - 1);
                    int mA = __shfl(m_l, jn, 32);
                    rA = mA & 31;
                    const float4* hp = (const float4*)(h1 + (size_t)(mA >> 5) * 32);
#pragma unroll
                    for (int c = 0; c < 8; ++c) A[c] = hp[c];
                }
                {  // compute edge j+1 from B
                    const float* wp = W2T + (rB * 32 + o) * W2T_PAD;
#pragma unroll
                    for (int c = 0; c < 8; ++c) {
                        float4 w4 = *(const float4*)(wp + c * 4);
                        acc = fmaf(B[c].x, w4.x, acc);
                        acc = fmaf(B[c].y, w4.y, acc);
                        acc = fmaf(B[c].z, w4.z, acc);
                        acc = fmaf(B[c].w, w4.w, acc);
                    }
                }
                j += 2;
            }
            if (j < cnt) {  // odd tail: edge j sits in A
                const float* wp = W2T + (rA * 32 + o) * W2T_PAD;
#pragma unroll
                for (int c = 0; c < 8; ++c) {
                    float4 w4 = *(const float4*)(wp + c * 4);
                    acc = fmaf(A[c].x, w4.x, acc);
                    acc = fmaf(A[c].y, w4.y, acc);
                    acc = fmaf(A[c].z, w4.z, acc);
                    acc = fmaf(A[c].w, w4.w, acc);
                }
            }
        }
        acc += b2[o];
        float h2v = fmaxf(acc, 0.f);

        // layer 3 via cross-lane broadcast of h2
        float acc3 = b3[o];
#pragma unroll
        for (int i = 0; i < 32; ++i) {
            float hi = __shfl(h2v, i, 32);
            acc3 = fmaf(hi, W3s[i * 32 + o], acc3);
        }
        out[(size_t)hw * 32 + o] = acc3;
    }
}

// ---------------- Host launcher ----------------

extern "C" void kernel_launch(void* const* d_in, const int* in_sizes, int n_in,
                              void* d_out, int out_size, void* d_ws, size_t ws_size,
                              hipStream_t stream) {
    const int* src   = (const int*)d_in[0];
    const int* dst   = (const int*)d_in[1];
    const int* etype = (const int*)d_in[2];
    const float* W1  = (const float*)d_in[4];
    const float* b1  = (const float*)d_in[5];
    const float* W2  = (const float*)d_in[6];
    const float* b2  = (const float*)d_in[7];
    const float* W3  = (const float*)d_in[8];
    const float* b3  = (const float*)d_in[9];
    float* out = (float*)d_out;

    int E = in_sizes[0];
    int N = out_size / 32;

    char* ws = (char*)d_ws;
    size_t off = 0;
    auto alloc = [&](size_t bytes) {
        void* p = ws + off;
        off = (off + bytes + 255) & ~(size_t)255;
        return p;
    };
    float* h1      = (float*)alloc((size_t)N * 32 * 4);
    int* cnt2      = (int*)alloc((size_t)N * NUM_RELS * 4);
    int* row_start = (int*)alloc((size_t)(N + 1) * 4);
    int* cursor    = (int*)alloc((size_t)N * 4);
    int* bsum      = (int*)alloc(256 * 4);
    int* smeta     = (int*)alloc((size_t)E * 4);

    hipMemsetAsync(cnt2, 0, (size_t)N * NUM_RELS * 4, stream);
    hist2_kernel<<<(E + 255) / 256, 256, 0, stream>>>(dst, etype, cnt2, E);
    int NB = (N + 2047) / 2048;
    scan1_kernel<<<NB, 256, 0, stream>>>(cnt2, row_start, bsum, N);
    scan2_kernel<<<1, 256, 0, stream>>>(bsum, NB);
    scan3_kernel<<<(N + 1 + 255) / 256, 256, 0, stream>>>(row_start, cursor, bsum, N, E);
    scatter_kernel<<<(E + 255) / 256, 256, 0, stream>>>(src, dst, etype, cursor, smeta, E);
    layer1_kernel<<<(N + 7) / 8, 256, 0, stream>>>(cnt2, W1, b1, h1, N);

    const int LDS23 = (W2T_FLOATS + 32 * 32) * 4;
    hipFuncSetAttribute(reinterpret_cast<const void*>(layer23_kernel),
                        hipFuncAttributeMaxDynamicSharedMemorySize, LDS23);
    layer23_kernel<<<1024, 1024, LDS23, stream>>>(h1, row_start, smeta,
                                                  W2, b2, W3, b3, out, N);
}

// Round 5
// 641.980 us; speedup vs baseline: 1.2594x; 1.2594x over previous
//
#include <hip/hip_runtime.h>
#include <hip/hip_bf16.h>

#define NUM_RELS 19

// ---------------- CSR build ----------------
// cnt2[v*19+r] = #edges with dst=v, etype=r  (feeds both scan1 and layer1)

__global__ void hist2_kernel(const int* __restrict__ dst, const int* __restrict__ etype,
                             int* __restrict__ cnt2, int E) {
    int e = blockIdx.x * blockDim.x + threadIdx.x;
    if (e < E) atomicAdd(&cnt2[dst[e] * NUM_RELS + etype[e]], 1);
}

// chunk = 2048 nodes per block (256 threads x 8 nodes); per-node count = sum of 19 cnt2 entries
__global__ void scan1_kernel(const int* __restrict__ cnt2, int* __restrict__ row_start,
                             int* __restrict__ bsum, int N) {
    __shared__ int lds[256];
    int t = threadIdx.x;
    int base = blockIdx.x * 2048 + t * 8;
    int v[8];
    int s = 0;
#pragma unroll
    for (int k = 0; k < 8; ++k) {
        int c = 0;
        if (base + k < N) {
            const int* p = cnt2 + (size_t)(base + k) * NUM_RELS;
#pragma unroll
            for (int r = 0; r < NUM_RELS; ++r) c += p[r];
        }
        v[k] = c;
        s += c;
    }
    lds[t] = s;
    __syncthreads();
    for (int off = 1; off < 256; off <<= 1) {
        int x = (t >= off) ? lds[t - off] : 0;
        __syncthreads();
        lds[t] += x;
        __syncthreads();
    }
    int run = lds[t] - s;  // exclusive prefix of this thread's chunk
#pragma unroll
    for (int k = 0; k < 8; ++k) {
        if (base + k < N) row_start[base + k] = run;
        run += v[k];
    }
    if (t == 255) bsum[blockIdx.x] = lds[255];
}

__global__ void scan2_kernel(int* __restrict__ bsum, int NB) {
    __shared__ int lds[256];
    int t = threadIdx.x;
    int v = (t < NB) ? bsum[t] : 0;
    lds[t] = v;
    __syncthreads();
    for (int off = 1; off < 256; off <<= 1) {
        int x = (t >= off) ? lds[t - off] : 0;
        __syncthreads();
        lds[t] += x;
        __syncthreads();
    }
    if (t < NB) bsum[t] = lds[t] - v;  // exclusive
}

__global__ void scan3_kernel(int* __restrict__ row_start, int* __restrict__ cursor,
                             const int* __restrict__ bsum, int N, int E) {
    int i = blockIdx.x * blockDim.x + threadIdx.x;
    if (i < N) {
        int v = row_start[i] + bsum[i >> 11];
        row_start[i] = v;
        cursor[i] = v;
    } else if (i == N) {
        row_start[N] = E;
    }
}

// scatter packed edge meta (src<<5 | etype) into CSR order — ONE int per edge
__global__ void scatter_kernel(const int* __restrict__ src, const int* __restrict__ dst,
                               const int* __restrict__ etype, int* __restrict__ cursor,
                               int* __restrict__ smeta, int E) {
    int e = blockIdx.x * blockDim.x + threadIdx.x;
    if (e < E) {
        int p = atomicAdd(&cursor[dst[e]], 1);
        smeta[p] = (src[e] << 5) | etype[e];
    }
}

// ---------------- Layer 1 (closed form): h1[v][o] = relu(b1[o] + sum_r cnt2[v][r]*W1[r][o]) ----------------

__global__ __launch_bounds__(256) void layer1_kernel(
    const int* __restrict__ cnt2, const float* __restrict__ W1,
    const float* __restrict__ b1, float* __restrict__ h1, int N) {
    __shared__ float W1s[NUM_RELS * 32];
    __shared__ float b1s[32];
    for (int t = threadIdx.x; t < NUM_RELS * 32; t += blockDim.x) W1s[t] = W1[t];
    if (threadIdx.x < 32) b1s[threadIdx.x] = b1[threadIdx.x];
    __syncthreads();

    int hw = (blockIdx.x * blockDim.x + threadIdx.x) >> 5;  // node id
    int o = threadIdx.x & 31;
    if (hw >= N) return;
    const int* c = cnt2 + (size_t)hw * NUM_RELS;
    float acc = b1s[o];
#pragma unroll
    for (int r = 0; r < NUM_RELS; ++r) acc += (float)c[r] * W1s[r * 32 + o];
    h1[(size_t)hw * 32 + o] = fmaxf(acc, 0.f);
}

// ---------------- Transform: g[r][v][o] = sum_i h1[v][i] * W2[r][i][o]  (bf16 output) ----------------
// One relation per blockIdx.y; lane o holds W2[r][:,o] column in 32 VGPRs (no LDS).
// Per node: coalesced h1 dword load, 32x (shfl-broadcast + fma), bf16 store.

#define TF_NODES_PER_HW 8  // nodes per half-wave per block

__global__ __launch_bounds__(256) void transform_kernel(
    const float* __restrict__ h1, const float* __restrict__ W2,
    __hip_bfloat16* __restrict__ g, int N) {
    int r = blockIdx.y;
    int o = threadIdx.x & 31;
    int hwid = threadIdx.x >> 5;  // 0..7

    float wv[32];
    const float* wp = W2 + r * 1024 + o;
#pragma unroll
    for (int i = 0; i < 32; ++i) wv[i] = wp[i * 32];

    __hip_bfloat16* gr = g + (size_t)r * N * 32;
    int v0 = (blockIdx.x * 8 + hwid) * TF_NODES_PER_HW;
#pragma unroll
    for (int k = 0; k < TF_NODES_PER_HW; ++k) {
        int v = v0 + k;
        if (v >= N) break;
        float h = h1[(size_t)v * 32 + o];
        float acc = 0.f;
#pragma unroll
        for (int i = 0; i < 32; ++i) acc = fmaf(__shfl(h, i, 32), wv[i], acc);
        gr[(size_t)v * 32 + o] = __float2bfloat16(acc);
    }
}

// ---------------- Edge phase + layer 3 fused ----------------
// Per 32-lane half-wave: one node, lane = output channel o.
// Per edge: ONE coalesced bf16 load of g[r][src][o] + one add. No LDS/W in loop.

__global__ __launch_bounds__(1024) void edge23_kernel(
    const __hip_bfloat16* __restrict__ g, const int* __restrict__ row_start,
    const int* __restrict__ smeta, const float* __restrict__ b2,
    const float* __restrict__ W3, const float* __restrict__ b3,
    float* __restrict__ out, int N) {
    __shared__ float W3s[1024];
    __shared__ float b2s[32], b3s[32];
    W3s[threadIdx.x] = W3[threadIdx.x];
    if (threadIdx.x < 32) {
        b2s[threadIdx.x] = b2[threadIdx.x];
        b3s[threadIdx.x] = b3[threadIdx.x];
    }
    __syncthreads();

    int o = threadIdx.x & 31;
    int hw = blockIdx.x * 32 + (threadIdx.x >> 5);  // node id
    if (hw >= N) return;
    int start = row_start[hw], end = row_start[hw + 1];
    const int sN32 = N * 32;  // fits int: 3.2M; max addr 19*3.2M = 60.8M

    float acc = b2s[o];
    for (int base = start; base < end; base += 32) {
        int idx = base + o;
        int m_l = (idx < end) ? smeta[idx] : 0;  // coalesced packed (src<<5|etype)
        int cnt = min(32, end - base);
        int j = 0;
        for (; j + 4 <= cnt; j += 4) {
            int m0 = __shfl(m_l, j + 0, 32);
            int m1 = __shfl(m_l, j + 1, 32);
            int m2 = __shfl(m_l, j + 2, 32);
            int m3 = __shfl(m_l, j + 3, 32);
            float x0 = __bfloat162float(g[(m0 & 31) * sN32 + (m0 >> 5) * 32 + o]);
            float x1 = __bfloat162float(g[(m1 & 31) * sN32 + (m1 >> 5) * 32 + o]);
            float x2 = __bfloat162float(g[(m2 & 31) * sN32 + (m2 >> 5) * 32 + o]);
            float x3 = __bfloat162float(g[(m3 & 31) * sN32 + (m3 >> 5) * 32 + o]);
            acc += (x0 + x1) + (x2 + x3);
        }
        for (; j < cnt; ++j) {
            int m = __shfl(m_l, j, 32);
            acc += __bfloat162float(g[(m & 31) * sN32 + (m >> 5) * 32 + o]);
        }
    }
    float h2v = fmaxf(acc, 0.f);

    // layer 3 via cross-lane broadcast of h2
    float acc3 = b3s[o];
#pragma unroll
    for (int i = 0; i < 32; ++i) {
        float hi = __shfl(h2v, i, 32);
        acc3 = fmaf(hi, W3s[i * 32 + o], acc3);
    }
    out[(size_t)hw * 32 + o] = acc3;
}

// ---------------- Host launcher ----------------

extern "C" void kernel_launch(void* const* d_in, const int* in_sizes, int n_in,
                              void* d_out, int out_size, void* d_ws, size_t ws_size,
                              hipStream_t stream) {
    const int* src   = (const int*)d_in[0];
    const int* dst   = (const int*)d_in[1];
    const int* etype = (const int*)d_in[2];
    const float* W1  = (const float*)d_in[4];
    const float* b1  = (const float*)d_in[5];
    const float* W2  = (const float*)d_in[6];
    const float* b2  = (const float*)d_in[7];
    const float* W3  = (const float*)d_in[8];
    const float* b3  = (const float*)d_in[9];
    float* out = (float*)d_out;

    int E = in_sizes[0];
    int N = out_size / 32;

    char* ws = (char*)d_ws;
    size_t off = 0;
    auto alloc = [&](size_t bytes) {
        void* p = ws + off;
        off = (off + bytes + 255) & ~(size_t)255;
        return p;
    };
    float* h1           = (float*)alloc((size_t)N * 32 * 4);
    int* cnt2           = (int*)alloc((size_t)N * NUM_RELS * 4);
    int* row_start      = (int*)alloc((size_t)(N + 1) * 4);
    int* cursor         = (int*)alloc((size_t)N * 4);
    int* bsum           = (int*)alloc(256 * 4);
    int* smeta          = (int*)alloc((size_t)E * 4);
    __hip_bfloat16* g   = (__hip_bfloat16*)alloc((size_t)NUM_RELS * N * 32 * 2);

    hipMemsetAsync(cnt2, 0, (size_t)N * NUM_RELS * 4, stream);
    hist2_kernel<<<(E + 255) / 256, 256, 0, stream>>>(dst, etype, cnt2, E);
    int NB = (N + 2047) / 2048;
    scan1_kernel<<<NB, 256, 0, stream>>>(cnt2, row_start, bsum, N);
    scan2_kernel<<<1, 256, 0, stream>>>(bsum, NB);
    scan3_kernel<<<(N + 1 + 255) / 256, 256, 0, stream>>>(row_start, cursor, bsum, N, E);
    scatter_kernel<<<(E + 255) / 256, 256, 0, stream>>>(src, dst, etype, cursor, smeta, E);
    layer1_kernel<<<(N + 7) / 8, 256, 0, stream>>>(cnt2, W1, b1, h1, N);

    // transform: grid (node_tiles, relations)
    int ntiles = (N + 8 * TF_NODES_PER_HW - 1) / (8 * TF_NODES_PER_HW);
    dim3 tgrid(ntiles, NUM_RELS);
    transform_kernel<<<tgrid, 256, 0, stream>>>(h1, W2, g, N);

    edge23_kernel<<<(N + 31) / 32, 1024, 0, stream>>>(g, row_start, smeta, b2, W3, b3, out, N);
}

// Round 6
// 340.733 us; speedup vs baseline: 2.3729x; 1.8841x over previous
//
#include <hip/hip_runtime.h>

#define NUM_RELS 19

typedef _Float16 half8 __attribute__((ext_vector_type(8)));
typedef float floatx4 __attribute__((ext_vector_type(4)));

// ---------------- CSR build ----------------
// cnt2[v*19+r] = #edges with dst=v, etype=r  (feeds both scan1 and layer1)

__global__ void hist2_kernel(const int* __restrict__ dst, const int* __restrict__ etype,
                             int* __restrict__ cnt2, int E) {
    int e = blockIdx.x * blockDim.x + threadIdx.x;
    if (e < E) atomicAdd(&cnt2[dst[e] * NUM_RELS + etype[e]], 1);
}

// chunk = 2048 nodes per block (256 threads x 8 nodes); per-node count = sum of 19 cnt2 entries
__global__ void scan1_kernel(const int* __restrict__ cnt2, int* __restrict__ row_start,
                             int* __restrict__ bsum, int N) {
    __shared__ int lds[256];
    int t = threadIdx.x;
    int base = blockIdx.x * 2048 + t * 8;
    int v[8];
    int s = 0;
#pragma unroll
    for (int k = 0; k < 8; ++k) {
        int c = 0;
        if (base + k < N) {
            const int* p = cnt2 + (size_t)(base + k) * NUM_RELS;
#pragma unroll
            for (int r = 0; r < NUM_RELS; ++r) c += p[r];
        }
        v[k] = c;
        s += c;
    }
    lds[t] = s;
    __syncthreads();
    for (int off = 1; off < 256; off <<= 1) {
        int x = (t >= off) ? lds[t - off] : 0;
        __syncthreads();
        lds[t] += x;
        __syncthreads();
    }
    int run = lds[t] - s;  // exclusive prefix of this thread's chunk
#pragma unroll
    for (int k = 0; k < 8; ++k) {
        if (base + k < N) row_start[base + k] = run;
        run += v[k];
    }
    if (t == 255) bsum[blockIdx.x] = lds[255];
}

__global__ void scan2_kernel(int* __restrict__ bsum, int NB) {
    __shared__ int lds[256];
    int t = threadIdx.x;
    int v = (t < NB) ? bsum[t] : 0;
    lds[t] = v;
    __syncthreads();
    for (int off = 1; off < 256; off <<= 1) {
        int x = (t >= off) ? lds[t - off] : 0;
        __syncthreads();
        lds[t] += x;
        __syncthreads();
    }
    if (t < NB) bsum[t] = lds[t] - v;  // exclusive
}

__global__ void scan3_kernel(int* __restrict__ row_start, int* __restrict__ cursor,
                             const int* __restrict__ bsum, int N, int E) {
    int i = blockIdx.x * blockDim.x + threadIdx.x;
    if (i < N) {
        int v = row_start[i] + bsum[i >> 11];
        row_start[i] = v;
        cursor[i] = v;
    } else if (i == N) {
        row_start[N] = E;
    }
}

// scatter packed edge meta (src<<5 | etype) into CSR order — ONE int per edge
__global__ void scatter_kernel(const int* __restrict__ src, const int* __restrict__ dst,
                               const int* __restrict__ etype, int* __restrict__ cursor,
                               int* __restrict__ smeta, int E) {
    int e = blockIdx.x * blockDim.x + threadIdx.x;
    if (e < E) {
        int p = atomicAdd(&cursor[dst[e]], 1);
        smeta[p] = (src[e] << 5) | etype[e];
    }
}

// ---------------- Layer 1 (closed form): h1[v][o] = relu(b1[o] + sum_r cnt2[v][r]*W1[r][o]) ----------------

__global__ __launch_bounds__(256) void layer1_kernel(
    const int* __restrict__ cnt2, const float* __restrict__ W1,
    const float* __restrict__ b1, float* __restrict__ h1, int N) {
    __shared__ float W1s[NUM_RELS * 32];
    __shared__ float b1s[32];
    for (int t = threadIdx.x; t < NUM_RELS * 32; t += blockDim.x) W1s[t] = W1[t];
    if (threadIdx.x < 32) b1s[threadIdx.x] = b1[threadIdx.x];
    __syncthreads();

    int hw = (blockIdx.x * blockDim.x + threadIdx.x) >> 5;  // node id
    int o = threadIdx.x & 31;
    if (hw >= N) return;
    const int* c = cnt2 + (size_t)hw * NUM_RELS;
    float acc = b1s[o];
#pragma unroll
    for (int r = 0; r < NUM_RELS; ++r) acc += (float)c[r] * W1s[r * 32 + o];
    h1[(size_t)hw * 32 + o] = fmaxf(acc, 0.f);
}

// ---------------- W2 -> f16 B-fragment swizzle ----------------
// B-fragment layout for mfma_f32_16x16x32_f16: lane l, elem j holds B[k=(l>>4)*8+j][n=(l&15)].
// W2F[((r*2+nt)*64 + lane)*8 + j] = W2[r][k][nt*16 + (lane&15)]  -> transform reads one
// coalesced 16B dwordx2 per (r, n-tile).

__global__ void w2swz_kernel(const float* __restrict__ W2, _Float16* __restrict__ W2F) {
    int idx = blockIdx.x * blockDim.x + threadIdx.x;
    if (idx >= NUM_RELS * 2 * 64 * 8) return;
    int j = idx & 7, lane = (idx >> 3) & 63, nt = (idx >> 9) & 1, r = idx >> 10;
    int k = (lane >> 4) * 8 + j, n = nt * 16 + (lane & 15);
    W2F[idx] = (_Float16)W2[r * 1024 + k * 32 + n];
}

// ---------------- Transform via MFMA: g[r] = h1 @ W2[r]  (f16 output) ----------------
// One wave per 16-node tile. A-frag: A[m=lane&15][k=quad*8+j] (m120-verified layout).
// Per (r, n-tile): 1 dwordx2 B-frag load (L1-hot 38KB) + 1 MFMA (full K=32).
// C/D map: col=lane&15, row=quad*4+reg (m89/m91-verified). No LDS, no shfl.

__global__ __launch_bounds__(256) void transform_kernel(
    const float* __restrict__ h1, const _Float16* __restrict__ W2F,
    _Float16* __restrict__ g, int N) {
    int lane = threadIdx.x & 63;
    int tile = blockIdx.x * 4 + (threadIdx.x >> 6);
    int v0 = tile * 16;
    if (v0 >= N) return;

    const float* hrow = h1 + (size_t)(v0 + (lane & 15)) * 32 + (lane >> 4) * 8;
    float4 p0 = *(const float4*)hrow;
    float4 p1 = *(const float4*)(hrow + 4);
    half8 a;
    a[0] = (_Float16)p0.x; a[1] = (_Float16)p0.y; a[2] = (_Float16)p0.z; a[3] = (_Float16)p0.w;
    a[4] = (_Float16)p1.x; a[5] = (_Float16)p1.y; a[6] = (_Float16)p1.z; a[7] = (_Float16)p1.w;

    floatx4 zero = {0.f, 0.f, 0.f, 0.f};
    int row = (lane >> 4) * 4;
    int col = lane & 15;
    for (int r = 0; r < NUM_RELS; ++r) {
        _Float16* gbase = g + ((size_t)r * N + v0) * 32;
#pragma unroll
        for (int nt = 0; nt < 2; ++nt) {
            half8 b = *(const half8*)(W2F + ((r * 2 + nt) * 64 + lane) * 8);
            floatx4 d = __builtin_amdgcn_mfma_f32_16x16x32_f16(a, b, zero, 0, 0, 0);
#pragma unroll
            for (int reg = 0; reg < 4; ++reg) {
                gbase[(row + reg) * 32 + nt * 16 + col] = (_Float16)d[reg];
            }
        }
    }
}

// ---------------- Edge phase + layer 3 fused ----------------
// Per 32-lane half-wave: one node, lane = output channel o.
// Per edge: ONE coalesced f16 load of g[r][src][o] + one add. No LDS/W in loop.

__global__ __launch_bounds__(1024) void edge23_kernel(
    const _Float16* __restrict__ g, const int* __restrict__ row_start,
    const int* __restrict__ smeta, const float* __restrict__ b2,
    const float* __restrict__ W3, const float* __restrict__ b3,
    float* __restrict__ out, int N) {
    __shared__ float W3s[1024];
    __shared__ float b2s[32], b3s[32];
    W3s[threadIdx.x] = W3[threadIdx.x];
    if (threadIdx.x < 32) {
        b2s[threadIdx.x] = b2[threadIdx.x];
        b3s[threadIdx.x] = b3[threadIdx.x];
    }
    __syncthreads();

    int o = threadIdx.x & 31;
    int hw = blockIdx.x * 32 + (threadIdx.x >> 5);  // node id
    if (hw >= N) return;
    int start = row_start[hw], end = row_start[hw + 1];
    const int sN32 = N * 32;  // fits int: 3.2M; max addr 19*3.2M = 60.8M

    float acc = b2s[o];
    for (int base = start; base < end; base += 32) {
        int idx = base + o;
        int m_l = (idx < end) ? smeta[idx] : 0;  // coalesced packed (src<<5|etype)
        int cnt = min(32, end - base);
        int j = 0;
        for (; j + 4 <= cnt; j += 4) {
            int m0 = __shfl(m_l, j + 0, 32);
            int m1 = __shfl(m_l, j + 1, 32);
            int m2 = __shfl(m_l, j + 2, 32);
            int m3 = __shfl(m_l, j + 3, 32);
            float x0 = (float)g[(m0 & 31) * sN32 + (m0 >> 5) * 32 + o];
            float x1 = (float)g[(m1 & 31) * sN32 + (m1 >> 5) * 32 + o];
            float x2 = (float)g[(m2 & 31) * sN32 + (m2 >> 5) * 32 + o];
            float x3 = (float)g[(m3 & 31) * sN32 + (m3 >> 5) * 32 + o];
            acc += (x0 + x1) + (x2 + x3);
        }
        for (; j < cnt; ++j) {
            int m = __shfl(m_l, j, 32);
            acc += (float)g[(m & 31) * sN32 + (m >> 5) * 32 + o];
        }
    }
    float h2v = fmaxf(acc, 0.f);

    // layer 3 via cross-lane broadcast of h2
    float acc3 = b3s[o];
#pragma unroll
    for (int i = 0; i < 32; ++i) {
        float hi = __shfl(h2v, i, 32);
        acc3 = fmaf(hi, W3s[i * 32 + o], acc3);
    }
    out[(size_t)hw * 32 + o] = acc3;
}

// ---------------- Host launcher ----------------

extern "C" void kernel_launch(void* const* d_in, const int* in_sizes, int n_in,
                              void* d_out, int out_size, void* d_ws, size_t ws_size,
                              hipStream_t stream) {
    const int* src   = (const int*)d_in[0];
    const int* dst   = (const int*)d_in[1];
    const int* etype = (const int*)d_in[2];
    const float* W1  = (const float*)d_in[4];
    const float* b1  = (const float*)d_in[5];
    const float* W2  = (const float*)d_in[6];
    const float* b2  = (const float*)d_in[7];
    const float* W3  = (const float*)d_in[8];
    const float* b3  = (const float*)d_in[9];
    float* out = (float*)d_out;

    int E = in_sizes[0];
    int N = out_size / 32;

    char* ws = (char*)d_ws;
    size_t off = 0;
    auto alloc = [&](size_t bytes) {
        void* p = ws + off;
        off = (off + bytes + 255) & ~(size_t)255;
        return p;
    };
    float* h1      = (float*)alloc((size_t)N * 32 * 4);
    int* cnt2      = (int*)alloc((size_t)N * NUM_RELS * 4);
    int* row_start = (int*)alloc((size_t)(N + 1) * 4);
    int* cursor    = (int*)alloc((size_t)N * 4);
    int* bsum      = (int*)alloc(256 * 4);
    int* smeta     = (int*)alloc((size_t)E * 4);
    _Float16* g    = (_Float16*)alloc((size_t)NUM_RELS * N * 32 * 2);
    _Float16* W2F  = (_Float16*)alloc((size_t)NUM_RELS * 2 * 64 * 8 * 2);

    hipMemsetAsync(cnt2, 0, (size_t)N * NUM_RELS * 4, stream);
    hist2_kernel<<<(E + 255) / 256, 256, 0, stream>>>(dst, etype, cnt2, E);
    int NB = (N + 2047) / 2048;
    scan1_kernel<<<NB, 256, 0, stream>>>(cnt2, row_start, bsum, N);
    scan2_kernel<<<1, 256, 0, stream>>>(bsum, NB);
    scan3_kernel<<<(N + 1 + 255) / 256, 256, 0, stream>>>(row_start, cursor, bsum, N, E);
    scatter_kernel<<<(E + 255) / 256, 256, 0, stream>>>(src, dst, etype, cursor, smeta, E);
    layer1_kernel<<<(N + 7) / 8, 256, 0, stream>>>(cnt2, W1, b1, h1, N);

    w2swz_kernel<<<(NUM_RELS * 2 * 64 * 8 + 255) / 256, 256, 0, stream>>>(W2, W2F);

    int ntiles = (N + 15) / 16;
    transform_kernel<<<(ntiles + 3) / 4, 256, 0, stream>>>(h1, W2F, g, N);

    edge23_kernel<<<(N + 31) / 32, 1024, 0, stream>>>(g, row_start, smeta, b2, W3, b3, out, N);
}